// Round 10
// baseline (32.354 us; speedup 1.0000x reference)
//
#include <hip/hip_runtime.h>

// ROI-Align (bilinear, half-pixel) — B=1, H=W=128, C=512, POOL=7, N ROIs.
// Output layout: (N, 1, 7, 7, C) flat = ((roi*49 + py*7 + px) * C + c).
//
// Round-10 (= round-9 resubmit after infra failure): persistent grid-stride
// blocks + 1-deep register prefetch.
//   - 8-way channel partition: chunk = blockIdx.x & 7 → XCD (round-robin);
//     each XCD reads only its 128x128x64 sub-map (4 MiB, L2-resident).
//   - Grid = 2048 blocks (8/CU). Each thread owns (chunk, lane, bin%4096)
//     and loops bins with stride 4096 (~12 iterations).
//   - Software pipeline: next iteration's 4 corner loads are issued before
//     the current bin's interpolation consumes its (already-arrived) data,
//     keeping ≥4 loads in flight per thread to hide L2/HBM latency.
//   - Non-temporal output stores (streaming, never re-read).
// Block = 256 threads = 16 bins x 16 lanes; lane = one float4 of the chunk.

#define POOLN 7
#define FM_W 128
#define FM_C 512
#define NXCD 8
#define CHUNK_C 64                    // channels per chunk
#define BINS_PER_ITER 16              // bins per block per iteration
#define NGROUPS 256                   // block-groups (per chunk)
#define STRIDE (BINS_PER_ITER * NGROUPS)   // 4096 bins/iteration grid-wide

typedef float f32x4 __attribute__((ext_vector_type(4)));

__global__ __launch_bounds__(256) void roi_align_kernel(
    const float* __restrict__ fm,
    const int* __restrict__ rois,
    float* __restrict__ out,
    int n_bins)
{
    const int chunk = blockIdx.x & (NXCD - 1);   // → XCD id (heuristic)
    const int group = blockIdx.x >> 3;           // 0..255
    const int lane  = threadIdx.x & 15;          // float4 index within chunk
    const int sub   = threadIdx.x >> 4;          // bin slot within block
    const int coff  = chunk * CHUNK_C + lane * 4;

    // Compute the 4 corner offsets + weights for bin b.
    auto coords = [&](int b, int& oa, int& ob, int& od, int& oe,
                      float& wxo, float& wyo) {
        const int roi = b / 49;
        const int rem = b - roi * 49;
        const int py  = rem / 7;
        const int px  = rem - py * 7;

        const int4 r = reinterpret_cast<const int4*>(rois)[roi];
        const int x1 = r.x, y1 = r.y, x2 = r.z, y2 = r.w;

        const float sizy = (float)(y2 - y1);
        float cy = ((float)py + 0.5f) * (sizy / (float)POOLN) - 0.5f;
        cy = fminf(fmaxf(cy, 0.0f), sizy - 1.0f);
        const float ys = cy + (float)y1;
        const int   y0 = (int)floorf(ys);
        const int   yb = min(y0 + 1, y2 - 1);
        wyo = ys - (float)y0;

        const float sizx = (float)(x2 - x1);
        float cx = ((float)px + 0.5f) * (sizx / (float)POOLN) - 0.5f;
        cx = fminf(fmaxf(cx, 0.0f), sizx - 1.0f);
        const float xs = cx + (float)x1;
        const int   x0 = (int)floorf(xs);
        const int   xb = min(x0 + 1, x2 - 1);
        wxo = xs - (float)x0;

        oa = (y0 * FM_W + x0) * FM_C + coff;
        ob = (y0 * FM_W + xb) * FM_C + coff;
        od = (yb * FM_W + x0) * FM_C + coff;
        oe = (yb * FM_W + xb) * FM_C + coff;
    };

    int bin = group * BINS_PER_ITER + sub;       // < 4096 < n_bins always
    int oa, ob, od, oe;
    float wx, wy;
    coords(bin, oa, ob, od, oe, wx, wy);
    f32x4 a  = *reinterpret_cast<const f32x4*>(fm + oa);
    f32x4 bb = *reinterpret_cast<const f32x4*>(fm + ob);
    f32x4 d  = *reinterpret_cast<const f32x4*>(fm + od);
    f32x4 e  = *reinterpret_cast<const f32x4*>(fm + oe);

    for (;;) {
        const int nbin = bin + STRIDE;
        const bool nv = nbin < n_bins;           // block-uniform (16 | STRIDE)

        f32x4 na, nb, nd, ne;
        float nwx = 0.f, nwy = 0.f;
        if (nv) {
            int qa, qb, qd, qe;
            coords(nbin, qa, qb, qd, qe, nwx, nwy);
            na = *reinterpret_cast<const f32x4*>(fm + qa);
            nb = *reinterpret_cast<const f32x4*>(fm + qb);
            nd = *reinterpret_cast<const f32x4*>(fm + qd);
            ne = *reinterpret_cast<const f32x4*>(fm + qe);
        }

        // Consume current bin (its loads were issued one iteration ago).
        const f32x4 top = a + (bb - a) * wx;
        const f32x4 bot = d + (e - d) * wx;
        const f32x4 res = top + (bot - top) * wy;
        f32x4* o = reinterpret_cast<f32x4*>(out + (size_t)bin * FM_C + coff);
        __builtin_nontemporal_store(res, o);

        if (!nv) break;
        bin = nbin; wx = nwx; wy = nwy;
        a = na; bb = nb; d = nd; e = ne;
    }
}

extern "C" void kernel_launch(void* const* d_in, const int* in_sizes, int n_in,
                              void* d_out, int out_size, void* d_ws, size_t ws_size,
                              hipStream_t stream) {
    const float* fm   = (const float*)d_in[0];
    const int*   rois = (const int*)d_in[1];
    float*       out  = (float*)d_out;

    const int N      = in_sizes[1] / 4;          // 1024 ROIs
    const int n_bins = N * POOLN * POOLN;        // 50176
    dim3 grid(NGROUPS * NXCD);                   // 2048 persistent blocks
    roi_align_kernel<<<grid, 256, 0, stream>>>(fm, rois, out, n_bins);
}